// Round 1
// baseline (625.422 us; speedup 1.0000x reference)
//
#include <hip/hip_runtime.h>

// Wilson Dslash, 32^4 lattice, DeGrand-Rossi basis, separate re/im fp32 planes.
// res(x) = -0.5 * sum_mu [ (I-g_mu) U_mu(x) psi(x+mu) + (I+g_mu) U_mu(x-mu)^dag psi(x-mu) ]
// Spin-projection trick: (I -+ g_mu) v is rank-2 -> project to 2 half-spinors h0,h1,
// color-multiply only those (halves the 3x3 complex matvec work), reconstruct lower
// spin rows from g0,g1 with the fixed phase per mu (derived & row-checked vs gamma defs).

static constexpr int SITES = 32 * 32 * 32 * 32;

__device__ __forceinline__ void load12(const float* __restrict__ p, float* v) {
    const float4* q = reinterpret_cast<const float4*>(p);  // site*12 floats = 48B, 16B-aligned
    float4 a = q[0], b = q[1], c = q[2];
    v[0] = a.x; v[1] = a.y; v[2]  = a.z; v[3]  = a.w;
    v[4] = b.x; v[5] = b.y; v[6]  = b.z; v[7]  = b.w;
    v[8] = c.x; v[9] = c.y; v[10] = c.z; v[11] = c.w;
}

__global__ __launch_bounds__(256) void wilson_dslash_kernel(
    const float* __restrict__ psi_re, const float* __restrict__ psi_im,
    const float* __restrict__ U_re,   const float* __restrict__ U_im,
    float* __restrict__ out_re,       float* __restrict__ out_im)
{
    const int site = blockIdx.x * 256 + threadIdx.x;
    const int t =  site        & 31;
    const int z = (site >> 5)  & 31;
    const int y = (site >> 10) & 31;
    const int x = (site >> 15) & 31;

    float ar[12], ai[12];   // accumulator, index = spin*3 + color
#pragma unroll
    for (int k = 0; k < 12; ++k) { ar[k] = 0.f; ai[k] = 0.f; }

    const int coord[4]  = {x, y, z, t};
    const int stride[4] = {32768, 1024, 32, 1};

#pragma unroll
    for (int mu = 0; mu < 4; ++mu) {
        const int cmu = coord[mu];
        const int S   = stride[mu];
        const int nf  = site + (cmu == 31 ? -31 * S : S);   // x + mu (periodic)
        const int nb  = site + (cmu == 0  ?  31 * S : -S);  // x - mu (periodic)

        float vr[12], vi[12];
        float hr[6], hi[6];   // half-spinor, index = s*3 + color, s in {0,1}
        float gr[6], gi[6];
        float ur[9], ui[9];

        // ================= forward hop: (I - g_mu) U_mu(x) psi(x+mu) =================
        load12(psi_re + nf * 12, vr);
        load12(psi_im + nf * 12, vi);
#pragma unroll
        for (int c = 0; c < 3; ++c) {
            if (mu == 0) {          // h0 = v0 - i v3 ; h1 = v1 - i v2
                hr[c]     = vr[c]     + vi[9 + c];  hi[c]     = vi[c]     - vr[9 + c];
                hr[3 + c] = vr[3 + c] + vi[6 + c];  hi[3 + c] = vi[3 + c] - vr[6 + c];
            } else if (mu == 1) {   // h0 = v0 + v3 ; h1 = v1 - v2
                hr[c]     = vr[c]     + vr[9 + c];  hi[c]     = vi[c]     + vi[9 + c];
                hr[3 + c] = vr[3 + c] - vr[6 + c];  hi[3 + c] = vi[3 + c] - vi[6 + c];
            } else if (mu == 2) {   // h0 = v0 - i v2 ; h1 = v1 + i v3
                hr[c]     = vr[c]     + vi[6 + c];  hi[c]     = vi[c]     - vr[6 + c];
                hr[3 + c] = vr[3 + c] - vi[9 + c];  hi[3 + c] = vi[3 + c] + vr[9 + c];
            } else {                // h0 = v0 - v2 ; h1 = v1 - v3
                hr[c]     = vr[c]     - vr[6 + c];  hi[c]     = vi[c]     - vi[6 + c];
                hr[3 + c] = vr[3 + c] - vr[9 + c];  hi[3 + c] = vi[3 + c] - vi[9 + c];
            }
        }
        {
            const float* pur = U_re + (site * 4 + mu) * 9;
            const float* pui = U_im + (site * 4 + mu) * 9;
#pragma unroll
            for (int k = 0; k < 9; ++k) { ur[k] = pur[k]; ui[k] = pui[k]; }
        }
        // g[s][i] = sum_j U[i][j] h[s][j]   (complex)
#pragma unroll
        for (int s = 0; s < 2; ++s)
#pragma unroll
            for (int i = 0; i < 3; ++i) {
                float rr = 0.f, im = 0.f;
#pragma unroll
                for (int j = 0; j < 3; ++j) {
                    rr += ur[i * 3 + j] * hr[s * 3 + j] - ui[i * 3 + j] * hi[s * 3 + j];
                    im += ur[i * 3 + j] * hi[s * 3 + j] + ui[i * 3 + j] * hr[s * 3 + j];
                }
                gr[s * 3 + i] = rr; gi[s * 3 + i] = im;
            }
        // reconstruct: rows 0,1 += g0,g1 always; rows 2,3 per mu
#pragma unroll
        for (int c = 0; c < 3; ++c) {
            ar[c]     += gr[c];      ai[c]     += gi[c];
            ar[3 + c] += gr[3 + c];  ai[3 + c] += gi[3 + c];
            if (mu == 0) {          // r2 += i g1 ; r3 += i g0
                ar[6 + c] -= gi[3 + c];  ai[6 + c] += gr[3 + c];
                ar[9 + c] -= gi[c];      ai[9 + c] += gr[c];
            } else if (mu == 1) {   // r2 += -g1 ; r3 += g0
                ar[6 + c] -= gr[3 + c];  ai[6 + c] -= gi[3 + c];
                ar[9 + c] += gr[c];      ai[9 + c] += gi[c];
            } else if (mu == 2) {   // r2 += i g0 ; r3 += -i g1
                ar[6 + c] -= gi[c];      ai[6 + c] += gr[c];
                ar[9 + c] += gi[3 + c];  ai[9 + c] -= gr[3 + c];
            } else {                // r2 += -g0 ; r3 += -g1
                ar[6 + c] -= gr[c];      ai[6 + c] -= gi[c];
                ar[9 + c] -= gr[3 + c];  ai[9 + c] -= gi[3 + c];
            }
        }

        // ================= backward hop: (I + g_mu) U_mu(x-mu)^dag psi(x-mu) =================
        load12(psi_re + nb * 12, vr);
        load12(psi_im + nb * 12, vi);
#pragma unroll
        for (int c = 0; c < 3; ++c) {
            if (mu == 0) {          // h0 = v0 + i v3 ; h1 = v1 + i v2
                hr[c]     = vr[c]     - vi[9 + c];  hi[c]     = vi[c]     + vr[9 + c];
                hr[3 + c] = vr[3 + c] - vi[6 + c];  hi[3 + c] = vi[3 + c] + vr[6 + c];
            } else if (mu == 1) {   // h0 = v0 - v3 ; h1 = v1 + v2
                hr[c]     = vr[c]     - vr[9 + c];  hi[c]     = vi[c]     - vi[9 + c];
                hr[3 + c] = vr[3 + c] + vr[6 + c];  hi[3 + c] = vi[3 + c] + vi[6 + c];
            } else if (mu == 2) {   // h0 = v0 + i v2 ; h1 = v1 - i v3
                hr[c]     = vr[c]     - vi[6 + c];  hi[c]     = vi[c]     + vr[6 + c];
                hr[3 + c] = vr[3 + c] + vi[9 + c];  hi[3 + c] = vi[3 + c] - vr[9 + c];
            } else {                // h0 = v0 + v2 ; h1 = v1 + v3
                hr[c]     = vr[c]     + vr[6 + c];  hi[c]     = vi[c]     + vi[6 + c];
                hr[3 + c] = vr[3 + c] + vr[9 + c];  hi[3 + c] = vi[3 + c] + vi[9 + c];
            }
        }
        {
            const float* pur = U_re + (nb * 4 + mu) * 9;
            const float* pui = U_im + (nb * 4 + mu) * 9;
#pragma unroll
            for (int k = 0; k < 9; ++k) { ur[k] = pur[k]; ui[k] = pui[k]; }
        }
        // g[s][i] = sum_j conj(U[j][i]) h[s][j]
#pragma unroll
        for (int s = 0; s < 2; ++s)
#pragma unroll
            for (int i = 0; i < 3; ++i) {
                float rr = 0.f, im = 0.f;
#pragma unroll
                for (int j = 0; j < 3; ++j) {
                    rr += ur[j * 3 + i] * hr[s * 3 + j] + ui[j * 3 + i] * hi[s * 3 + j];
                    im += ur[j * 3 + i] * hi[s * 3 + j] - ui[j * 3 + i] * hr[s * 3 + j];
                }
                gr[s * 3 + i] = rr; gi[s * 3 + i] = im;
            }
#pragma unroll
        for (int c = 0; c < 3; ++c) {
            ar[c]     += gr[c];      ai[c]     += gi[c];
            ar[3 + c] += gr[3 + c];  ai[3 + c] += gi[3 + c];
            if (mu == 0) {          // r2 += -i g1 ; r3 += -i g0
                ar[6 + c] += gi[3 + c];  ai[6 + c] -= gr[3 + c];
                ar[9 + c] += gi[c];      ai[9 + c] -= gr[c];
            } else if (mu == 1) {   // r2 += g1 ; r3 += -g0
                ar[6 + c] += gr[3 + c];  ai[6 + c] += gi[3 + c];
                ar[9 + c] -= gr[c];      ai[9 + c] -= gi[c];
            } else if (mu == 2) {   // r2 += -i g0 ; r3 += i g1
                ar[6 + c] += gi[c];      ai[6 + c] -= gr[c];
                ar[9 + c] -= gi[3 + c];  ai[9 + c] += gr[3 + c];
            } else {                // r2 += g0 ; r3 += g1
                ar[6 + c] += gr[c];      ai[6 + c] += gi[c];
                ar[9 + c] += gr[3 + c];  ai[9 + c] += gi[3 + c];
            }
        }
    }

    // out = -0.5 * acc, vectorized stores
    float4* orp = reinterpret_cast<float4*>(out_re + site * 12);
    float4* oip = reinterpret_cast<float4*>(out_im + site * 12);
    orp[0] = make_float4(-0.5f * ar[0], -0.5f * ar[1], -0.5f * ar[2],  -0.5f * ar[3]);
    orp[1] = make_float4(-0.5f * ar[4], -0.5f * ar[5], -0.5f * ar[6],  -0.5f * ar[7]);
    orp[2] = make_float4(-0.5f * ar[8], -0.5f * ar[9], -0.5f * ar[10], -0.5f * ar[11]);
    oip[0] = make_float4(-0.5f * ai[0], -0.5f * ai[1], -0.5f * ai[2],  -0.5f * ai[3]);
    oip[1] = make_float4(-0.5f * ai[4], -0.5f * ai[5], -0.5f * ai[6],  -0.5f * ai[7]);
    oip[2] = make_float4(-0.5f * ai[8], -0.5f * ai[9], -0.5f * ai[10], -0.5f * ai[11]);
}

extern "C" void kernel_launch(void* const* d_in, const int* in_sizes, int n_in,
                              void* d_out, int out_size, void* d_ws, size_t ws_size,
                              hipStream_t stream) {
    const float* psi_re = (const float*)d_in[0];
    const float* psi_im = (const float*)d_in[1];
    const float* U_re   = (const float*)d_in[2];
    const float* U_im   = (const float*)d_in[3];
    // d_in[4..7] are the projector matrices; hardcoded in-kernel.
    float* out_re = (float*)d_out;
    float* out_im = out_re + (size_t)SITES * 12;

    wilson_dslash_kernel<<<SITES / 256, 256, 0, stream>>>(
        psi_re, psi_im, U_re, U_im, out_re, out_im);
}